// Round 5
// baseline (16.432 us; speedup 1.0000x reference)
//
#include <hip/hip_runtime.h>

#define NK 8
#define NR 32
#define NF 16
#define NB 32768
#define LOG2E 1.4426950408889634f

typedef _Float16 f16x8 __attribute__((ext_vector_type(8)));
typedef float    f32x4 __attribute__((ext_vector_type(4)));

// One fused kernel. Block = 512 = 8 waves; wave k <-> branch k, 64 batch elems/block.
// Each wave folds its branch's params into MFMA A-fragments IN REGISTERS:
//   S1[r,b] = sum_f A_f x^2 + B_f x  (+C_r)   rows 0-31
//   S2[r,b] = sum_f W_f x            (+bias)  rows 32-63
// via mfma_f32_16x16x32_f16 with B-operand [x^2(16) | x(16)].
__global__ __launch_bounds__(512, 4) void hfnn_fused(
    const float* __restrict__ data, const float* __restrict__ mu,
    const float* __restrict__ sg,   const float* __restrict__ w3,
    const float* __restrict__ w5,   const float* __restrict__ b5,
    float* __restrict__ out)
{
    __shared__ float cbuf[NK][64];   // C (rows 0-31) / bias (rows 32-63) per branch
    __shared__ float tl[NK][64];     // tsk[k][b] for the final combine

    const int lane = threadIdx.x & 63;
    const int k    = threadIdx.x >> 6;    // wave id == branch
    const int g    = lane >> 4;           // k-group 0..3
    const int col  = lane & 15;           // batch col within 16-tile

    // ---- issue x loads FIRST so HBM latency hides under the param folding ----
    const int bbase = blockIdx.x * 64;
    float4 xr[4][2];
#pragma unroll
    for (int c = 0; c < 4; ++c) {
        const float* xp = data + ((size_t)k * NB + (bbase + c * 16 + col)) * NF + (g & 1) * 8;
        xr[c][0] = reinterpret_cast<const float4*>(xp)[0];
        xr[c][1] = reinterpret_cast<const float4*>(xp)[1];
    }

    // ---- fold params into A-fragments (registers), coalesced loads ----
    f16x8 afrag[4];
#pragma unroll
    for (int t = 0; t < 2; ++t) {
        const int row = 16 * t + col;                      // rule r = row
        const float* sp = sg + ((k * NR + row) * NF + (g & 1) * 8);
        const float* mp = mu + ((k * NR + row) * NF + (g & 1) * 8);
        float4 s0 = reinterpret_cast<const float4*>(sp)[0];
        float4 s1 = reinterpret_cast<const float4*>(sp)[1];
        float4 m0 = reinterpret_cast<const float4*>(mp)[0];
        float4 m1 = reinterpret_cast<const float4*>(mp)[1];
        float sv[8] = {s0.x,s0.y,s0.z,s0.w,s1.x,s1.y,s1.z,s1.w};
        float mv[8] = {m0.x,m0.y,m0.z,m0.w,m1.x,m1.y,m1.z,m1.w};
        f16x8 fr;
#pragma unroll
        for (int j = 0; j < 8; ++j) {
            float a = -(LOG2E * 0.5f) / (sv[j] * sv[j]);
            float v = (g < 2) ? a : (-2.0f * a * mv[j]);   // g<2: A-half, g>=2: B-half
            fr[j] = (_Float16)v;
        }
        afrag[t] = fr;
    }
#pragma unroll
    for (int t = 2; t < 4; ++t) {
        const int r = 16 * (t - 2) + col;                  // rule index
        f16x8 fr;
        if (g < 2) {                                       // x^2-half multiplies 0
#pragma unroll
            for (int j = 0; j < 8; ++j) fr[j] = (_Float16)0.0f;
        } else {                                           // x-half multiplies W_f
            const float* wp = w3 + ((k * NR + r) * (NF + 1) + (g & 1) * 8);
#pragma unroll
            for (int j = 0; j < 8; ++j) fr[j] = (_Float16)wp[j];   // stride-17 rows: scalar loads
        }
        afrag[t] = fr;
    }

    // ---- C_r / bias_r: one value per row via LDS exchange ----
    {
        float v;
        if (lane < 32) {
            const float* sp = sg + (k * NR + lane) * NF;
            const float* mp = mu + (k * NR + lane) * NF;
            float c = 0.f;
#pragma unroll
            for (int i = 0; i < 4; ++i) {
                float4 s4 = reinterpret_cast<const float4*>(sp)[i];
                float4 m4 = reinterpret_cast<const float4*>(mp)[i];
                c = fmaf((-(LOG2E*0.5f))/(s4.x*s4.x)*m4.x, m4.x, c);
                c = fmaf((-(LOG2E*0.5f))/(s4.y*s4.y)*m4.y, m4.y, c);
                c = fmaf((-(LOG2E*0.5f))/(s4.z*s4.z)*m4.z, m4.z, c);
                c = fmaf((-(LOG2E*0.5f))/(s4.w*s4.w)*m4.w, m4.w, c);
            }
            v = c;
        } else {
            v = w3[(k * NR + (lane - 32)) * (NF + 1) + NF];
        }
        cbuf[k][lane] = v;
    }
    __syncthreads();

    f32x4 cbv[4];
#pragma unroll
    for (int t = 0; t < 4; ++t)
        cbv[t] = *reinterpret_cast<const f32x4*>(&cbuf[k][16 * t + g * 4]);

    // ---- main loop: 4 batch tiles of 16, 4 MFMA each ----
#pragma unroll
    for (int c = 0; c < 4; ++c) {
        float4 v0 = xr[c][0], v1 = xr[c][1];
        if (g < 2) {                                       // k-groups 0,1 supply x^2
            v0.x *= v0.x; v0.y *= v0.y; v0.z *= v0.z; v0.w *= v0.w;
            v1.x *= v1.x; v1.y *= v1.y; v1.z *= v1.z; v1.w *= v1.w;
        }
        f16x8 bf;
        bf[0] = (_Float16)v0.x; bf[1] = (_Float16)v0.y;
        bf[2] = (_Float16)v0.z; bf[3] = (_Float16)v0.w;
        bf[4] = (_Float16)v1.x; bf[5] = (_Float16)v1.y;
        bf[6] = (_Float16)v1.z; bf[7] = (_Float16)v1.w;

        f32x4 a0 = __builtin_amdgcn_mfma_f32_16x16x32_f16(afrag[0], bf, cbv[0], 0, 0, 0);
        f32x4 a1 = __builtin_amdgcn_mfma_f32_16x16x32_f16(afrag[1], bf, cbv[1], 0, 0, 0);
        f32x4 a2 = __builtin_amdgcn_mfma_f32_16x16x32_f16(afrag[2], bf, cbv[2], 0, 0, 0);
        f32x4 a3 = __builtin_amdgcn_mfma_f32_16x16x32_f16(afrag[3], bf, cbv[3], 0, 0, 0);

        float num = 0.f, den = 0.f;
#pragma unroll
        for (int j = 0; j < 4; ++j) {
            float e0 = __builtin_amdgcn_exp2f(a0[j]);      // rules g*4+j
            float e1 = __builtin_amdgcn_exp2f(a1[j]);      // rules 16+g*4+j
            den += e0 + e1;
            num = fmaf(e0, a2[j], num);
            num = fmaf(e1, a3[j], num);
        }
        num += __shfl_xor(num, 16);
        den += __shfl_xor(den, 16);
        num += __shfl_xor(num, 32);
        den += __shfl_xor(den, 32);
        if (lane < 16) tl[k][c * 16 + lane] = __fdividef(num, den);
    }
    __syncthreads();

    if (threadIdx.x < 64) {               // wave 0: branch combine + 2-class softmax
        float l0 = b5[0], l1 = b5[1];
#pragma unroll
        for (int kk = 0; kk < NK; ++kk) {
            float t = tl[kk][lane];
            l0 = fmaf(t, w5[kk],      l0);
            l1 = fmaf(t, w5[NK + kk], l1);
        }
        float m  = fmaxf(l0, l1);
        float e0 = __expf(l0 - m);
        float e1 = __expf(l1 - m);
        float inv = __fdividef(1.f, e0 + e1);
        *reinterpret_cast<float2*>(out + (size_t)(blockIdx.x * 64 + lane) * 2) =
            make_float2(e0 * inv, e1 * inv);
    }
}

extern "C" void kernel_launch(void* const* d_in, const int* in_sizes, int n_in,
                              void* d_out, int out_size, void* d_ws, size_t ws_size,
                              hipStream_t stream) {
    const float* data = (const float*)d_in[0];
    const float* mu   = (const float*)d_in[1];
    const float* sg   = (const float*)d_in[2];
    const float* w3   = (const float*)d_in[3];
    const float* w5   = (const float*)d_in[4];
    const float* b5   = (const float*)d_in[5];
    float* out = (float*)d_out;

    hfnn_fused<<<NB / 64, 512, 0, stream>>>(data, mu, sg, w3, w5, b5, out);
}

// Round 6
// 12.654 us; speedup vs baseline: 1.2985x; 1.2985x over previous
//
#include <hip/hip_runtime.h>

#define NK 8
#define NR 32
#define NF 16
#define NB 32768
#define LOG2E 1.4426950408889634f

typedef _Float16 f16x8 __attribute__((ext_vector_type(8)));
typedef float    f32x4 __attribute__((ext_vector_type(4)));

// One fused kernel. Block = 512 = 8 waves; wave k <-> branch k, 64 batch elems/block.
//   S1[r,b] = sum_f A_f x^2 + B_f x (+C_r)   MFMA rows 0-31   (A=-log2e/2sig^2, B=-2A mu, C=sum A mu^2)
//   S2[r,b] = sum_f W_f x          (+bias)   MFMA rows 32-63
// via mfma_f32_16x16x32_f16, B-operand = [x^2(16) | x(16)].
// Fold is in-register: sg/mu loaded ONCE; C via shfl_xor+shfl; bias via broadcast gathers.
__global__ __launch_bounds__(512, 4) void hfnn_fused(
    const float* __restrict__ data, const float* __restrict__ mu,
    const float* __restrict__ sg,   const float* __restrict__ w3,
    const float* __restrict__ w5,   const float* __restrict__ b5,
    float* __restrict__ out)
{
    __shared__ float tl[NK][64];          // tsk[k][b]

    const int lane = threadIdx.x & 63;
    const int k    = threadIdx.x >> 6;    // wave id == branch
    const int g    = lane >> 4;           // k-group 0..3
    const int col  = lane & 15;

    // ---- x loads first: HBM latency hides under the param fold ----
    const int bbase = blockIdx.x * 64;
    float4 xr[4][2];
#pragma unroll
    for (int c = 0; c < 4; ++c) {
        const float* xp = data + ((size_t)k * NB + (bbase + c * 16 + col)) * NF + (g & 1) * 8;
        xr[c][0] = reinterpret_cast<const float4*>(xp)[0];
        xr[c][1] = reinterpret_cast<const float4*>(xp)[1];
    }

    f16x8 afrag[4];
    f32x4 cbv[4];

    // ---- tiles 0,1: Gaussian fragments + C via shuffles (sg/mu loaded once) ----
#pragma unroll
    for (int t = 0; t < 2; ++t) {
        const float* sp = sg + ((k * NR + 16 * t + col) * NF + (g & 1) * 8);
        const float* mp = mu + ((k * NR + 16 * t + col) * NF + (g & 1) * 8);
        float4 s0 = reinterpret_cast<const float4*>(sp)[0];
        float4 s1 = reinterpret_cast<const float4*>(sp)[1];
        float4 m0 = reinterpret_cast<const float4*>(mp)[0];
        float4 m1 = reinterpret_cast<const float4*>(mp)[1];
        float sv[8] = {s0.x,s0.y,s0.z,s0.w,s1.x,s1.y,s1.z,s1.w};
        float mv[8] = {m0.x,m0.y,m0.z,m0.w,m1.x,m1.y,m1.z,m1.w};
        float cp = 0.f;
        f16x8 fr;
#pragma unroll
        for (int j = 0; j < 8; ++j) {
            float a = __fdividef(-(LOG2E * 0.5f), sv[j] * sv[j]);
            cp = fmaf(a * mv[j], mv[j], cp);
            float v = (g < 2) ? a : (-2.0f * a * mv[j]);
            fr[j] = (_Float16)v;
        }
        afrag[t] = fr;
        float C = cp + __shfl_xor(cp, 16);         // g0+g1 (and g2+g3) = full sum over f
        f32x4 cb;
        cb[0] = __shfl(C, g * 4 + 0);
        cb[1] = __shfl(C, g * 4 + 1);
        cb[2] = __shfl(C, g * 4 + 2);
        cb[3] = __shfl(C, g * 4 + 3);
        cbv[t] = cb;
    }

    // ---- tiles 2,3: consequent fragments (x-half = W) + bias broadcast gathers ----
#pragma unroll
    for (int t = 2; t < 4; ++t) {
        f16x8 fr;
        if (g >= 2) {
            const float* wp = w3 + ((k * NR + 16 * (t - 2) + col) * (NF + 1) + (g & 1) * 8);
#pragma unroll
            for (int j = 0; j < 8; ++j) fr[j] = (_Float16)wp[j];
        } else {
#pragma unroll
            for (int j = 0; j < 8; ++j) fr[j] = (_Float16)0.0f;
        }
        afrag[t] = fr;
        f32x4 cb;
#pragma unroll
        for (int j = 0; j < 4; ++j)
            cb[j] = w3[(k * NR + 16 * (t - 2) + g * 4 + j) * (NF + 1) + NF];
        cbv[t] = cb;
    }

    // ---- main loop: 4 batch tiles of 16, 4 MFMA each ----
#pragma unroll
    for (int c = 0; c < 4; ++c) {
        float4 v0 = xr[c][0], v1 = xr[c][1];
        if (g < 2) {                               // k-groups 0,1 supply x^2
            v0.x *= v0.x; v0.y *= v0.y; v0.z *= v0.z; v0.w *= v0.w;
            v1.x *= v1.x; v1.y *= v1.y; v1.z *= v1.z; v1.w *= v1.w;
        }
        f16x8 bf;
        bf[0] = (_Float16)v0.x; bf[1] = (_Float16)v0.y;
        bf[2] = (_Float16)v0.z; bf[3] = (_Float16)v0.w;
        bf[4] = (_Float16)v1.x; bf[5] = (_Float16)v1.y;
        bf[6] = (_Float16)v1.z; bf[7] = (_Float16)v1.w;

        f32x4 a0 = __builtin_amdgcn_mfma_f32_16x16x32_f16(afrag[0], bf, cbv[0], 0, 0, 0);
        f32x4 a1 = __builtin_amdgcn_mfma_f32_16x16x32_f16(afrag[1], bf, cbv[1], 0, 0, 0);
        f32x4 a2 = __builtin_amdgcn_mfma_f32_16x16x32_f16(afrag[2], bf, cbv[2], 0, 0, 0);
        f32x4 a3 = __builtin_amdgcn_mfma_f32_16x16x32_f16(afrag[3], bf, cbv[3], 0, 0, 0);

        float num = 0.f, den = 0.f;
#pragma unroll
        for (int j = 0; j < 4; ++j) {
            float e0 = __builtin_amdgcn_exp2f(a0[j]);   // rules g*4+j
            float e1 = __builtin_amdgcn_exp2f(a1[j]);   // rules 16+g*4+j
            den += e0 + e1;
            num = fmaf(e0, a2[j], num);
            num = fmaf(e1, a3[j], num);
        }
        num += __shfl_xor(num, 16);
        den += __shfl_xor(den, 16);
        num += __shfl_xor(num, 32);
        den += __shfl_xor(den, 32);
        if (lane < 16) tl[k][c * 16 + lane] = __fdividef(num, den);
    }
    __syncthreads();

    if (threadIdx.x < 64) {               // wave 0: branch combine + 2-class softmax
        float l0 = b5[0], l1 = b5[1];
#pragma unroll
        for (int kk = 0; kk < NK; ++kk) {
            float t = tl[kk][lane];
            l0 = fmaf(t, w5[kk],      l0);
            l1 = fmaf(t, w5[NK + kk], l1);
        }
        float m  = fmaxf(l0, l1);
        float e0 = __expf(l0 - m);
        float e1 = __expf(l1 - m);
        float inv = __fdividef(1.f, e0 + e1);
        *reinterpret_cast<float2*>(out + (size_t)(blockIdx.x * 64 + lane) * 2) =
            make_float2(e0 * inv, e1 * inv);
    }
}

extern "C" void kernel_launch(void* const* d_in, const int* in_sizes, int n_in,
                              void* d_out, int out_size, void* d_ws, size_t ws_size,
                              hipStream_t stream) {
    const float* data = (const float*)d_in[0];
    const float* mu   = (const float*)d_in[1];
    const float* sg   = (const float*)d_in[2];
    const float* w3   = (const float*)d_in[3];
    const float* w5   = (const float*)d_in[4];
    const float* b5   = (const float*)d_in[5];
    float* out = (float*)d_out;

    hfnn_fused<<<NB / 64, 512, 0, stream>>>(data, mu, sg, w3, w5, b5, out);
}

// Round 7
// 9.778 us; speedup vs baseline: 1.6805x; 1.2941x over previous
//
#include <hip/hip_runtime.h>

#define NK 8
#define NR 32
#define NF 16
#define NB 32768
#define LOG2E 1.4426950408889634f

typedef _Float16 f16x8  __attribute__((ext_vector_type(8)));
typedef float    f32x16 __attribute__((ext_vector_type(16)));

// One fused kernel. Block = 512 = 8 waves; wave k <-> branch k, 64 batch elems/block.
// 32x32x16 f16 MFMA: rules = 32 rows in ONE tile.
//   S1[r,b] = sum_f A_f x^2 + B_f x (+C_r) : mfma(frA, x^2-frag, Cinit) then mfma(frB, x-frag, .)
//   S2[r,b] = sum_f W_f x           (+bias): mfma(frW, x-frag, BiasInit)
// Lane map: m = lane&31 (A-row = rule, B-col = batch col), h = lane>>5 (K-subhalf: features h*8..h*8+7).
// C/D: col = lane&31, row = (reg&3) + 8*(reg>>2) + 4*h   [guide m74, HW-verified]
__global__ __launch_bounds__(512, 4) void hfnn_fused(
    const float* __restrict__ data, const float* __restrict__ mu,
    const float* __restrict__ sg,   const float* __restrict__ w3,
    const float* __restrict__ w5,   const float* __restrict__ b5,
    float* __restrict__ out)
{
    __shared__ float tl[NK][64];          // tsk[k][b]

    const int lane = threadIdx.x & 63;
    const int k    = threadIdx.x >> 6;    // wave id == branch
    const int h    = lane >> 5;           // K-subhalf / rule-half selector
    const int m    = lane & 31;           // rule row (A) / batch col (B)

    // ---- x loads first: HBM latency hides under the fold ----
    const int bbase = blockIdx.x * 64;
    float4 xv[2][2];
#pragma unroll
    for (int tau = 0; tau < 2; ++tau) {
        const float* xp = data + ((size_t)k * NB + (bbase + tau * 32 + m)) * NF + h * 8;
        xv[tau][0] = reinterpret_cast<const float4*>(xp)[0];
        xv[tau][1] = reinterpret_cast<const float4*>(xp)[1];
    }

    // ---- fold: each lane covers rule m, features h*8..h*8+7 (zero redundancy) ----
    const float* sp = sg + ((size_t)(k * NR + m) * NF + h * 8);
    const float* mp = mu + ((size_t)(k * NR + m) * NF + h * 8);
    float4 s0 = reinterpret_cast<const float4*>(sp)[0];
    float4 s1 = reinterpret_cast<const float4*>(sp)[1];
    float4 m0 = reinterpret_cast<const float4*>(mp)[0];
    float4 m1 = reinterpret_cast<const float4*>(mp)[1];
    float sv[8] = {s0.x,s0.y,s0.z,s0.w,s1.x,s1.y,s1.z,s1.w};
    float mv[8] = {m0.x,m0.y,m0.z,m0.w,m1.x,m1.y,m1.z,m1.w};

    f16x8 frA, frB, frW;
    float cp = 0.f;
#pragma unroll
    for (int j = 0; j < 8; ++j) {
        float a = __fdividef(-(LOG2E * 0.5f), sv[j] * sv[j]);
        frA[j] = (_Float16)a;
        frB[j] = (_Float16)(-2.0f * a * mv[j]);
        cp = fmaf(a * mv[j], mv[j], cp);
    }
    float C = cp + __shfl_xor(cp, 32);    // full sum over 16 features for rule m

    const float* wp = w3 + (size_t)(k * NR + m) * (NF + 1) + h * 8;
#pragma unroll
    for (int j = 0; j < 8; ++j) frW[j] = (_Float16)wp[j];   // rows stride 17: scalar loads, L2-hot
    float bias = w3[(size_t)(k * NR + m) * (NF + 1) + NF];

    // ---- redistribute C/bias into accumulator-init layout (one-time, 32 bpermutes) ----
    f32x16 c1i, c2i;
#pragma unroll
    for (int reg = 0; reg < 16; ++reg) {
        const int row = (reg & 3) + 8 * (reg >> 2) + 4 * h;
        c1i[reg] = __shfl(C, row);
        c2i[reg] = __shfl(bias, row);
    }

    // ---- main: 2 batch tiles of 32 cols, 3 MFMA each ----
#pragma unroll
    for (int tau = 0; tau < 2; ++tau) {
        float4 v0 = xv[tau][0], v1 = xv[tau][1];
        f16x8 bf2, bf1;
        bf2[0] = (_Float16)v0.x; bf2[1] = (_Float16)v0.y;
        bf2[2] = (_Float16)v0.z; bf2[3] = (_Float16)v0.w;
        bf2[4] = (_Float16)v1.x; bf2[5] = (_Float16)v1.y;
        bf2[6] = (_Float16)v1.z; bf2[7] = (_Float16)v1.w;
        bf1[0] = (_Float16)(v0.x*v0.x); bf1[1] = (_Float16)(v0.y*v0.y);
        bf1[2] = (_Float16)(v0.z*v0.z); bf1[3] = (_Float16)(v0.w*v0.w);
        bf1[4] = (_Float16)(v1.x*v1.x); bf1[5] = (_Float16)(v1.y*v1.y);
        bf1[6] = (_Float16)(v1.z*v1.z); bf1[7] = (_Float16)(v1.w*v1.w);

        f32x16 s1a = __builtin_amdgcn_mfma_f32_32x32x16_f16(frA, bf1, c1i, 0, 0, 0);
        s1a        = __builtin_amdgcn_mfma_f32_32x32x16_f16(frB, bf2, s1a, 0, 0, 0);
        f32x16 s2a = __builtin_amdgcn_mfma_f32_32x32x16_f16(frW, bf2, c2i, 0, 0, 0);

        float num = 0.f, den = 0.f;
#pragma unroll
        for (int reg = 0; reg < 16; ++reg) {
            float e = __builtin_amdgcn_exp2f(s1a[reg]);
            den += e;
            num = fmaf(e, s2a[reg], num);
        }
        num += __shfl_xor(num, 32);       // combine the two rule-halves
        den += __shfl_xor(den, 32);
        if (h == 0) tl[k][tau * 32 + m] = __fdividef(num, den);
    }
    __syncthreads();

    if (threadIdx.x < 64) {               // wave 0: branch combine + 2-class softmax
        float l0 = b5[0], l1 = b5[1];
#pragma unroll
        for (int kk = 0; kk < NK; ++kk) {
            float t = tl[kk][lane];
            l0 = fmaf(t, w5[kk],      l0);
            l1 = fmaf(t, w5[NK + kk], l1);
        }
        float mx = fmaxf(l0, l1);
        float e0 = __expf(l0 - mx);
        float e1 = __expf(l1 - mx);
        float inv = __fdividef(1.f, e0 + e1);
        *reinterpret_cast<float2*>(out + (size_t)(blockIdx.x * 64 + lane) * 2) =
            make_float2(e0 * inv, e1 * inv);
    }
}

extern "C" void kernel_launch(void* const* d_in, const int* in_sizes, int n_in,
                              void* d_out, int out_size, void* d_ws, size_t ws_size,
                              hipStream_t stream) {
    const float* data = (const float*)d_in[0];
    const float* mu   = (const float*)d_in[1];
    const float* sg   = (const float*)d_in[2];
    const float* w3   = (const float*)d_in[3];
    const float* w5   = (const float*)d_in[4];
    const float* b5   = (const float*)d_in[5];
    float* out = (float*)d_out;

    hfnn_fused<<<NB / 64, 512, 0, stream>>>(data, mu, sg, w3, w5, b5, out);
}